// Round 3
// baseline (1199.629 us; speedup 1.0000x reference)
//
#include <hip/hip_runtime.h>
#include <hip/hip_bf16.h>

typedef unsigned short u16;
typedef unsigned int u32;
typedef __attribute__((ext_vector_type(8))) short s16x8;   // 8 bf16 (4 VGPRs)
typedef __attribute__((ext_vector_type(4))) float f32x4;

__device__ __forceinline__ u16 bf16bits(float v) {
    union { __hip_bfloat16 b; u16 u; } c;
    c.b = __float2bfloat16(v);
    return c.u;
}

// Reference-exact discretize (validated rounds 2-4).
__device__ __forceinline__ float disc1(float v, float mn, float rg, float s) {
    const float u = __fmul_rn(__fsub_rn(v, mn), s);
    const float rn = rintf(u);
    int idx;
    if (fabsf(u - rn) > 1e-3f) {
        idx = (int)ceilf(u) - 1;
    } else {
        int kc = (int)rn;
        kc = kc < 1 ? 1 : (kc > 24 ? 24 : kc);
        const float cf = __fdiv_rn((float)kc, 25.0f);
        const float b = __fadd_rn(mn, __fmul_rn(rg, cf));
        idx = (int)rn - 1 + ((b < v) ? 1 : 0);
    }
    idx = idx < 0 ? 0 : (idx > 24 ? 24 : idx);
    return (float)idx;
}

// ---------------- per-column min/max: 1024 blocks x 128 rows ----------------
__global__ void kminmax(const float* __restrict__ x, float* __restrict__ pmin,
                        float* __restrict__ pmax) {
    __shared__ float4 smn[512], smx[512];
    const int t = threadIdx.x;
    const int c4 = t & 127;
    const int ro = t >> 7;
    const size_t r0 = (size_t)blockIdx.x * 128;
    float4 mn = {1e30f, 1e30f, 1e30f, 1e30f};
    float4 mx = {-1e30f, -1e30f, -1e30f, -1e30f};
#pragma unroll 8
    for (int i = 0; i < 32; ++i) {
        const int row = ro + i * 4;
        const float4 v = ((const float4*)(x + (r0 + row) * 512))[c4];
        mn.x = fminf(mn.x, v.x); mn.y = fminf(mn.y, v.y);
        mn.z = fminf(mn.z, v.z); mn.w = fminf(mn.w, v.w);
        mx.x = fmaxf(mx.x, v.x); mx.y = fmaxf(mx.y, v.y);
        mx.z = fmaxf(mx.z, v.z); mx.w = fmaxf(mx.w, v.w);
    }
    smn[t] = mn; smx[t] = mx;
    __syncthreads();
    if (t < 128) {
#pragma unroll
        for (int p = 1; p < 4; ++p) {
            const float4 a = smn[t + p * 128], b = smx[t + p * 128];
            mn.x = fminf(mn.x, a.x); mn.y = fminf(mn.y, a.y);
            mn.z = fminf(mn.z, a.z); mn.w = fminf(mn.w, a.w);
            mx.x = fmaxf(mx.x, b.x); mx.y = fmaxf(mx.y, b.y);
            mx.z = fmaxf(mx.z, b.z); mx.w = fmaxf(mx.w, b.w);
        }
        ((float4*)(pmin + blockIdx.x * 512))[c4] = mn;
        ((float4*)(pmax + blockIdx.x * 512))[c4] = mx;
    }
}

__global__ void kred(const float* __restrict__ pmin, const float* __restrict__ pmax,
                     float* __restrict__ p2min, float* __restrict__ p2max, int per) {
    const int c = threadIdx.x;
    const int j = blockIdx.x;
    float mn = 1e30f, mx = -1e30f;
    for (int i = 0; i < per; ++i) {
        mn = fminf(mn, pmin[(size_t)(j * per + i) * 512 + c]);
        mx = fmaxf(mx, pmax[(size_t)(j * per + i) * 512 + c]);
    }
    p2min[j * 512 + c] = mn;
    p2max[j * 512 + c] = mx;
}

__global__ void kbounds(const float* __restrict__ p2min, const float* __restrict__ p2max,
                        float* __restrict__ cmin, float* __restrict__ crange,
                        float* __restrict__ sinv, int np, float* __restrict__ dloss) {
    const int c = threadIdx.x;
    float mn = 1e30f, mx = -1e30f;
    for (int p = 0; p < np; ++p) {
        mn = fminf(mn, p2min[p * 512 + c]);
        mx = fmaxf(mx, p2max[p * 512 + c]);
    }
    cmin[c] = mn;
    const float rg = __fsub_rn(mx, mn);
    crange[c] = rg;
    sinv[c] = __fdiv_rn(25.0f, rg);
    if (c == 0) dloss[0] = 0.0f;          // d2_loss
}

// ---------------- weight casts W[K,N] fp32 -> Wt[N,K] bf16 ----------------
__global__ void ktc_all(const float* __restrict__ W_in, const float* __restrict__ W_h,
                        const float* __restrict__ W_out,
                        __hip_bfloat16* __restrict__ WinT, __hip_bfloat16* __restrict__ WhT,
                        __hip_bfloat16* __restrict__ WoutT) {
    const int i = blockIdx.x * 256 + threadIdx.x;
    if (i < 512 * 512) {
        WinT[i] = __float2bfloat16(W_in[(size_t)(i & 511) * 512 + (i >> 9)]);
    } else if (i < 2 * 512 * 512) {
        const int j = i - 512 * 512;
        WhT[j] = __float2bfloat16(W_h[(size_t)(j & 511) * 512 + (j >> 9)]);
    } else if (i < 2 * 512 * 512 + 128 * 512) {
        const int j = i - 2 * 512 * 512;
        WoutT[j] = __float2bfloat16(W_out[(size_t)(j & 511) * 128 + (j >> 9)]);
    }
}

// ---------------- Fused discretize + 7-layer MLP, 64 rows/block ----------------
// RESTRUCTURED for occupancy: 64 batch rows per block, ONE 64-KB LDS act
// buffer, 512 threads, __launch_bounds__(512,4) -> 2 independent blocks/CU
// (128 KB LDS of 160) = 4 waves/SIMD. Block A's barriers / phase-B convoys
// now overlap block B's MFMA phase (cross-block TLP — the R1 post-mortem
// showed per-wave ILP couldn't fill these holes at 2 waves/SIMD lockstep).
// Manual double-buffers and bias hoists REMOVED: unified reg count must be
// <=128 (acc 64 + ~50 arch) or we drop to 8 waves/CU and lose the 2nd block.
// Wave w computes neurons w*64..w*64+63 for the block's 64 batch rows.
// Act layout: [row][k] bf16, 16B granule g stored at g^(row&7).
__global__ __launch_bounds__(512, 4) void megamlp(
    const float* __restrict__ x,
    const float* __restrict__ cmin, const float* __restrict__ crange,
    const float* __restrict__ sinv,
    const u16* __restrict__ WinT, const u16* __restrict__ WhT,
    const u16* __restrict__ WoutT,
    const float* __restrict__ b_in, const float* __restrict__ b_h,
    const float* __restrict__ b_out,
    float* __restrict__ out) {
    __shared__ __attribute__((aligned(16))) u16 act[64 * 512];   // 64 KB

    const int t = threadIdx.x;
    const int lane = t & 63;
    const int w = t >> 6;          // wave 0..7
    const int lr = lane & 15;
    const int kq = lane >> 4;      // 0..3
    const int xr = lr & 7;
    const size_t row0 = (size_t)blockIdx.x * 64;

    // ---- discretize 64 rows of x into act ----
    {
        const int c4 = t & 127;
        const int ro = t >> 7;             // 0..3
        const float4 mn4 = ((const float4*)cmin)[c4];
        const float4 rg4 = ((const float4*)crange)[c4];
        const float4 s4  = ((const float4*)sinv)[c4];
        const int g16 = c4 >> 1;
        const int hb  = (c4 & 1) << 3;
#pragma unroll 4
        for (int i = 0; i < 16; ++i) {
            const int row = ro + i * 4;          // 0..63
            const float4 v = ((const float4*)(x + (row0 + row) * 512))[c4];
            const u32 lo = (u32)bf16bits(disc1(v.x, mn4.x, rg4.x, s4.x))
                         | ((u32)bf16bits(disc1(v.y, mn4.y, rg4.y, s4.y)) << 16);
            const u32 hi = (u32)bf16bits(disc1(v.z, mn4.z, rg4.z, s4.z))
                         | ((u32)bf16bits(disc1(v.w, mn4.w, rg4.w, s4.w)) << 16);
            const int gg = g16 ^ (row & 7);
            *(uint2*)((char*)act + (row << 10) + (gg << 4) + hb) = make_uint2(lo, hi);
        }
    }
    __syncthreads();

    // ---- 6 hidden-shaped layers (512 -> 512), in-place ----
    for (int layer = 0; layer < 6; ++layer) {
        const u16* W = (layer == 0) ? WinT : WhT;
        const float* bias = (layer == 0) ? b_in : b_h;

        f32x4 acc[4][4] = {};
        const u16* wp0 = W + ((w * 64 + lr) << 9) + (kq << 3);

#pragma unroll
        for (int ks = 0; ks < 16; ++ks) {
            s16x8 aF[4], bF[4];
            const u16* wp = wp0 + ks * 32;
#pragma unroll
            for (int mt = 0; mt < 4; ++mt)
                aF[mt] = *(const s16x8*)(wp + (mt << 13));
            const int gg = ((ks << 2) | kq) ^ xr;
#pragma unroll
            for (int nt = 0; nt < 4; ++nt)
                bF[nt] = *(const s16x8*)((const char*)act + ((nt * 16 + lr) << 10) + (gg << 4));
#pragma unroll
            for (int mt = 0; mt < 4; ++mt)
#pragma unroll
                for (int nt = 0; nt < 4; ++nt)
                    acc[mt][nt] = __builtin_amdgcn_mfma_f32_16x16x32_bf16(
                        aF[mt], bF[nt], acc[mt][nt], 0, 0, 0);
        }
        __syncthreads();   // all reads done -> safe to overwrite in place

        // phase B: bias + relu -> bf16 -> act[batch][neuron-as-k], swizzled
#pragma unroll
        for (int mt = 0; mt < 4; ++mt) {
            const f32x4 bv = ((const f32x4*)bias)[w * 16 + mt * 4 + kq];
            const int g16 = w * 8 + mt * 2 + (kq >> 1);
#pragma unroll
            for (int nt = 0; nt < 4; ++nt) {
                const int batch = nt * 16 + lr;
                const float v0 = fmaxf(acc[mt][nt][0] + bv[0], 0.0f);
                const float v1 = fmaxf(acc[mt][nt][1] + bv[1], 0.0f);
                const float v2 = fmaxf(acc[mt][nt][2] + bv[2], 0.0f);
                const float v3 = fmaxf(acc[mt][nt][3] + bv[3], 0.0f);
                const u32 lo = (u32)bf16bits(v0) | ((u32)bf16bits(v1) << 16);
                const u32 hi = (u32)bf16bits(v2) | ((u32)bf16bits(v3) << 16);
                const int gg = g16 ^ (batch & 7);
                *(uint2*)((char*)act + (batch << 10) + (gg << 4) + ((kq & 1) << 3)) =
                    make_uint2(lo, hi);
            }
        }
        __syncthreads();
    }

    // ---- output layer: 128 neurons; wave w -> neurons w*16..w*16+15 ----
    {
        f32x4 acc[4] = {};
        const u16* wp = WoutT + ((w * 16 + lr) << 9) + (kq << 3);
#pragma unroll
        for (int ks = 0; ks < 16; ++ks) {
            const s16x8 aF = *(const s16x8*)(wp + ks * 32);
            const int gg = ((ks << 2) | kq) ^ xr;
#pragma unroll
            for (int nt = 0; nt < 4; ++nt) {
                const s16x8 bF = *(const s16x8*)((const char*)act + ((nt * 16 + lr) << 10) + (gg << 4));
                acc[nt] = __builtin_amdgcn_mfma_f32_16x16x32_bf16(
                    aF, bF, acc[nt], 0, 0, 0);
            }
        }
        __syncthreads();   // reads done; stage fp32 [64][128] in place

        const f32x4 bvo = ((const f32x4*)b_out)[w * 4 + kq];
        const int g16o = w * 4 + kq;
#pragma unroll
        for (int nt = 0; nt < 4; ++nt) {
            const int batch = nt * 16 + lr;
            const int gg = g16o ^ (batch & 7);
            float* p = (float*)((char*)act + (batch << 9) + (gg << 4));
#pragma unroll
            for (int r = 0; r < 4; ++r)
                p[r] = fmaxf(acc[nt][r] + bvo[r], 0.0f);
        }
    }
    __syncthreads();

    // ---- coalesced dump of staged [64][128] fp32 ----
    {
        const int n4 = t & 31;
        const int bo = t >> 5;          // 0..15
#pragma unroll
        for (int pp = 0; pp < 4; ++pp) {
            const int batch = pp * 16 + bo;
            const int gg = n4 ^ (batch & 7);
            const float4 v = *(const float4*)((const char*)act + (batch << 9) + (gg << 4));
            ((float4*)(out + (row0 + batch) * 128))[n4] = v;
        }
    }
}

extern "C" void kernel_launch(void* const* d_in, const int* in_sizes, int n_in,
                              void* d_out, int out_size, void* d_ws, size_t ws_size,
                              hipStream_t stream) {
    const float* x     = (const float*)d_in[0];
    const float* W_in  = (const float*)d_in[1];
    const float* b_in  = (const float*)d_in[2];
    const float* W_h   = (const float*)d_in[3];
    const float* b_h   = (const float*)d_in[4];
    const float* W_out = (const float*)d_in[5];
    const float* b_out = (const float*)d_in[6];
    float* out = (float*)d_out;

    const int B = in_sizes[0] / 512;       // 131072
    const int NP1 = B / 128;               // 1024 minmax partial blocks

    // workspace (~5.5 MB)
    __hip_bfloat16* WinT  = (__hip_bfloat16*)d_ws;           // 512*512
    __hip_bfloat16* WhT   = WinT + 512 * 512;                // 512*512
    __hip_bfloat16* WoutT = WhT + 512 * 512;                 // 128*512
    float* pmin   = (float*)(WoutT + 128 * 512);             // NP1*512
    float* pmax   = pmin + (size_t)NP1 * 512;                // NP1*512
    float* p2min  = pmax + (size_t)NP1 * 512;                // 64*512
    float* p2max  = p2min + 64 * 512;                        // 64*512
    float* cmin   = p2max + 64 * 512;                        // 512
    float* crange = cmin + 512;                              // 512
    float* sinv   = crange + 512;                            // 512

    kminmax<<<NP1, 512, 0, stream>>>(x, pmin, pmax);
    kred<<<64, 512, 0, stream>>>(pmin, pmax, p2min, p2max, NP1 / 64);
    kbounds<<<1, 512, 0, stream>>>(p2min, p2max, cmin, crange, sinv, 64,
                                   out + (size_t)B * 128);
    ktc_all<<<(2 * 512 * 512 + 128 * 512 + 255) / 256, 256, 0, stream>>>(
        W_in, W_h, W_out, WinT, WhT, WoutT);

    megamlp<<<B / 64, 512, 0, stream>>>(x, cmin, crange, sinv,
        (const u16*)WinT, (const u16*)WhT, (const u16*)WoutT,
        b_in, b_h, b_out, out);
}

// Round 5
// 932.029 us; speedup vs baseline: 1.2871x; 1.2871x over previous
//
#include <hip/hip_runtime.h>
#include <hip/hip_bf16.h>

typedef unsigned short u16;
typedef unsigned int u32;
typedef __attribute__((ext_vector_type(8))) short s16x8;    // 8 bf16 (4 VGPRs)
typedef __attribute__((ext_vector_type(4))) float f32x4;
typedef __attribute__((ext_vector_type(16))) float f32x16;  // 32x32 MFMA acc

__device__ __forceinline__ u16 bf16bits(float v) {
    union { __hip_bfloat16 b; u16 u; } c;
    c.b = __float2bfloat16(v);
    return c.u;
}

// Reference-exact discretize (validated rounds 2-4).
__device__ __forceinline__ float disc1(float v, float mn, float rg, float s) {
    const float u = __fmul_rn(__fsub_rn(v, mn), s);
    const float rn = rintf(u);
    int idx;
    if (fabsf(u - rn) > 1e-3f) {
        idx = (int)ceilf(u) - 1;
    } else {
        int kc = (int)rn;
        kc = kc < 1 ? 1 : (kc > 24 ? 24 : kc);
        const float cf = __fdiv_rn((float)kc, 25.0f);
        const float b = __fadd_rn(mn, __fmul_rn(rg, cf));
        idx = (int)rn - 1 + ((b < v) ? 1 : 0);
    }
    idx = idx < 0 ? 0 : (idx > 24 ? 24 : idx);
    return (float)idx;
}

// ---------------- per-column min/max: 1024 blocks x 128 rows ----------------
__global__ void kminmax(const float* __restrict__ x, float* __restrict__ pmin,
                        float* __restrict__ pmax) {
    __shared__ float4 smn[512], smx[512];
    const int t = threadIdx.x;
    const int c4 = t & 127;
    const int ro = t >> 7;
    const size_t r0 = (size_t)blockIdx.x * 128;
    float4 mn = {1e30f, 1e30f, 1e30f, 1e30f};
    float4 mx = {-1e30f, -1e30f, -1e30f, -1e30f};
#pragma unroll 8
    for (int i = 0; i < 32; ++i) {
        const int row = ro + i * 4;
        const float4 v = ((const float4*)(x + (r0 + row) * 512))[c4];
        mn.x = fminf(mn.x, v.x); mn.y = fminf(mn.y, v.y);
        mn.z = fminf(mn.z, v.z); mn.w = fminf(mn.w, v.w);
        mx.x = fmaxf(mx.x, v.x); mx.y = fmaxf(mx.y, v.y);
        mx.z = fmaxf(mx.z, v.z); mx.w = fmaxf(mx.w, v.w);
    }
    smn[t] = mn; smx[t] = mx;
    __syncthreads();
    if (t < 128) {
#pragma unroll
        for (int p = 1; p < 4; ++p) {
            const float4 a = smn[t + p * 128], b = smx[t + p * 128];
            mn.x = fminf(mn.x, a.x); mn.y = fminf(mn.y, a.y);
            mn.z = fminf(mn.z, a.z); mn.w = fminf(mn.w, a.w);
            mx.x = fmaxf(mx.x, b.x); mx.y = fmaxf(mx.y, b.y);
            mx.z = fmaxf(mx.z, b.z); mx.w = fmaxf(mx.w, b.w);
        }
        ((float4*)(pmin + blockIdx.x * 512))[c4] = mn;
        ((float4*)(pmax + blockIdx.x * 512))[c4] = mx;
    }
}

__global__ void kred(const float* __restrict__ pmin, const float* __restrict__ pmax,
                     float* __restrict__ p2min, float* __restrict__ p2max, int per) {
    const int c = threadIdx.x;
    const int j = blockIdx.x;
    float mn = 1e30f, mx = -1e30f;
    for (int i = 0; i < per; ++i) {
        mn = fminf(mn, pmin[(size_t)(j * per + i) * 512 + c]);
        mx = fmaxf(mx, pmax[(size_t)(j * per + i) * 512 + c]);
    }
    p2min[j * 512 + c] = mn;
    p2max[j * 512 + c] = mx;
}

__global__ void kbounds(const float* __restrict__ p2min, const float* __restrict__ p2max,
                        float* __restrict__ cmin, float* __restrict__ crange,
                        float* __restrict__ sinv, int np, float* __restrict__ dloss) {
    const int c = threadIdx.x;
    float mn = 1e30f, mx = -1e30f;
    for (int p = 0; p < np; ++p) {
        mn = fminf(mn, p2min[p * 512 + c]);
        mx = fmaxf(mx, p2max[p * 512 + c]);
    }
    cmin[c] = mn;
    const float rg = __fsub_rn(mx, mn);
    crange[c] = rg;
    sinv[c] = __fdiv_rn(25.0f, rg);
    if (c == 0) dloss[0] = 0.0f;          // d2_loss
}

// ---------------- weight casts W[K,N] fp32 -> Wt[N,K] bf16 ----------------
__global__ void ktc_all(const float* __restrict__ W_in, const float* __restrict__ W_h,
                        const float* __restrict__ W_out,
                        __hip_bfloat16* __restrict__ WinT, __hip_bfloat16* __restrict__ WhT,
                        __hip_bfloat16* __restrict__ WoutT) {
    const int i = blockIdx.x * 256 + threadIdx.x;
    if (i < 512 * 512) {
        WinT[i] = __float2bfloat16(W_in[(size_t)(i & 511) * 512 + (i >> 9)]);
    } else if (i < 2 * 512 * 512) {
        const int j = i - 512 * 512;
        WhT[j] = __float2bfloat16(W_h[(size_t)(j & 511) * 512 + (j >> 9)]);
    } else if (i < 2 * 512 * 512 + 128 * 512) {
        const int j = i - 2 * 512 * 512;
        WoutT[j] = __float2bfloat16(W_out[(size_t)(j & 511) * 128 + (j >> 9)]);
    }
}

// ---------------- Fused discretize + 7-layer MLP, 128 rows/block ----------------
// R4/R5: R0 structure (128 rows/block, 1 block/CU — R3's 64-row TLP variant
// regressed 41%: halving MFMA-per-weight-load ratio dominates occupancy).
// CHANGE vs R0: hidden layers use mfma_f32_32x32x16_bf16 (m119: 2495 vs 2075
// TF, +20% matrix-pipe efficiency; halves MFMA inst count at identical
// operand traffic). C/D layout (m74/m101): col=lane&31,
// row=(reg&3)+8*(reg>>2)+4*(lane>>5). A: row=lane&31, k=(lane>>5)*8+j.
// B: col=lane&31, same k. s_setprio(1) wraps MFMA clusters (T5).
// Output layer keeps the validated 16x16 path.
// Act layout per 64-row buffer: [row][k] bf16, 16B granule g at g^(row&7).
__global__ __launch_bounds__(512, 2) void megamlp(
    const float* __restrict__ x,
    const float* __restrict__ cmin, const float* __restrict__ crange,
    const float* __restrict__ sinv,
    const u16* __restrict__ WinT, const u16* __restrict__ WhT,
    const u16* __restrict__ WoutT,
    const float* __restrict__ b_in, const float* __restrict__ b_h,
    const float* __restrict__ b_out,
    float* __restrict__ out) {
    __shared__ __attribute__((aligned(16))) u16 actA[64 * 512];   // 64 KB
    __shared__ __attribute__((aligned(16))) u16 actB[64 * 512];   // 64 KB

    const int t = threadIdx.x;
    const int lane = t & 63;
    const int w = t >> 6;          // wave 0..7
    const int lr = lane & 15;
    const int kq = lane >> 4;      // 0..3
    const int xr = lr & 7;
    const int l31 = lane & 31;     // 32x32 fragment row/col
    const int lh = lane >> 5;      // 32x32 k-half (0/1)
    const size_t row0 = (size_t)blockIdx.x * 128;

    // ---- discretize 128 rows of x into actA (rows 0-63) / actB (64-127) ----
    {
        const int c4 = t & 127;
        const int ro = t >> 7;             // 0..3
        const float4 mn4 = ((const float4*)cmin)[c4];
        const float4 rg4 = ((const float4*)crange)[c4];
        const float4 s4  = ((const float4*)sinv)[c4];
        const int g16 = c4 >> 1;
        const int hb  = (c4 & 1) << 3;
#pragma unroll 8
        for (int i = 0; i < 32; ++i) {
            const int row = ro + i * 4;          // 0..127
            const float4 v = ((const float4*)(x + (row0 + row) * 512))[c4];
            const u32 lo = (u32)bf16bits(disc1(v.x, mn4.x, rg4.x, s4.x))
                         | ((u32)bf16bits(disc1(v.y, mn4.y, rg4.y, s4.y)) << 16);
            const u32 hi = (u32)bf16bits(disc1(v.z, mn4.z, rg4.z, s4.z))
                         | ((u32)bf16bits(disc1(v.w, mn4.w, rg4.w, s4.w)) << 16);
            const int rl = row & 63;
            const int gg = g16 ^ (rl & 7);
            char* base = (row < 64) ? (char*)actA : (char*)actB;
            *(uint2*)(base + (rl << 10) + (gg << 4) + hb) = make_uint2(lo, hi);
        }
    }
    __syncthreads();

    // ---- 6 hidden-shaped layers (512 -> 512), in-place, 32x32x16 MFMA ----
    for (int layer = 0; layer < 6; ++layer) {
        const u16* W = (layer == 0) ? WinT : WhT;
        const float* bias = (layer == 0) ? b_in : b_h;

        // acc[h][mt][nt]: h = row-buffer (64 rows), mt = neuron 32-tile,
        // nt = row 32-tile within buffer. 8 x 16 = 128 AGPRs.
        f32x16 acc[2][2][2] = {};
        // A (weights): neuron row = w*64 + mt*32 + l31; k = ks*16 + lh*8 + j
        const u16* wpA = W + ((w * 64 + l31) << 9) + (lh << 3);

#pragma unroll
        for (int ks = 0; ks < 32; ++ks) {
            s16x8 aF[2], bF[2][2];
#pragma unroll
            for (int mt = 0; mt < 2; ++mt)
                aF[mt] = *(const s16x8*)(wpA + (mt << 14) + (ks << 4));
            // B (act): local row rl = nt*32 + l31; granule g = 2*ks + lh,
            // stored at gg = g ^ (rl&7) = g ^ (l31&7)  [nt*32 == 0 mod 8]
            const int gg = ((ks << 1) | lh) ^ (l31 & 7);
#pragma unroll
            for (int h = 0; h < 2; ++h) {
                const char* ah = h ? (const char*)actB : (const char*)actA;
#pragma unroll
                for (int nt = 0; nt < 2; ++nt)
                    bF[h][nt] = *(const s16x8*)(ah + ((nt * 32 + l31) << 10) + (gg << 4));
            }
            __builtin_amdgcn_s_setprio(1);
#pragma unroll
            for (int h = 0; h < 2; ++h)
#pragma unroll
                for (int mt = 0; mt < 2; ++mt)
#pragma unroll
                    for (int nt = 0; nt < 2; ++nt)
                        acc[h][mt][nt] = __builtin_amdgcn_mfma_f32_32x32x16_bf16(
                            aF[mt], bF[h][nt], acc[h][mt][nt], 0, 0, 0);
            __builtin_amdgcn_s_setprio(0);
        }
        __syncthreads();   // all reads done -> safe to overwrite in place

        // phase B: bias + relu -> bf16 -> act[batch][neuron-as-k], swizzled.
        // Lane's 16 acc values: neuron = w*64 + mt*32 + 4*lh + 8*q + r
        // (q = reg>>2, r = reg&3), local row rl = nt*32 + l31.
#pragma unroll
        for (int mt = 0; mt < 2; ++mt) {
#pragma unroll
            for (int q = 0; q < 4; ++q) {
                const f32x4 bv = ((const f32x4*)bias)[w * 16 + mt * 8 + q * 2 + lh];
                const int g16 = w * 8 + mt * 4 + q;
#pragma unroll
                for (int h = 0; h < 2; ++h) {
                    char* ah = h ? (char*)actB : (char*)actA;
#pragma unroll
                    for (int nt = 0; nt < 2; ++nt) {
                        const int rl = nt * 32 + l31;
                        const float v0 = fmaxf(acc[h][mt][nt][q * 4 + 0] + bv[0], 0.0f);
                        const float v1 = fmaxf(acc[h][mt][nt][q * 4 + 1] + bv[1], 0.0f);
                        const float v2 = fmaxf(acc[h][mt][nt][q * 4 + 2] + bv[2], 0.0f);
                        const float v3 = fmaxf(acc[h][mt][nt][q * 4 + 3] + bv[3], 0.0f);
                        const u32 lo = (u32)bf16bits(v0) | ((u32)bf16bits(v1) << 16);
                        const u32 hi = (u32)bf16bits(v2) | ((u32)bf16bits(v3) << 16);
                        const int gg = g16 ^ (rl & 7);
                        *(uint2*)(ah + (rl << 10) + (gg << 4) + (lh << 3)) =
                            make_uint2(lo, hi);
                    }
                }
            }
        }
        __syncthreads();
    }

    // ---- output layer: 128 neurons; wave w -> neurons w*16..w*16+15 (16x16) ----
    {
        f32x4 acc[2][4] = {};
        const u16* wp = WoutT + ((w * 16 + lr) << 9) + (kq << 3);
#pragma unroll
        for (int ks = 0; ks < 16; ++ks) {
            const s16x8 aF = *(const s16x8*)(wp + ks * 32);
            const int gg = ((ks << 2) | kq) ^ xr;
            __builtin_amdgcn_s_setprio(1);
#pragma unroll
            for (int h = 0; h < 2; ++h) {
                const char* ah = h ? (const char*)actB : (const char*)actA;
#pragma unroll
                for (int nt = 0; nt < 4; ++nt) {
                    const s16x8 bF = *(const s16x8*)(ah + ((nt * 16 + lr) << 10) + (gg << 4));
                    acc[h][nt] = __builtin_amdgcn_mfma_f32_16x16x32_bf16(
                        aF, bF, acc[h][nt], 0, 0, 0);
                }
            }
            __builtin_amdgcn_s_setprio(0);
        }
        __syncthreads();   // reads done; stage fp32 [64][128] per half in place

        const f32x4 bvo = ((const f32x4*)b_out)[w * 4 + kq];
        const int g16o = w * 4 + kq;
#pragma unroll
        for (int h = 0; h < 2; ++h) {
            char* sh = h ? (char*)actB : (char*)actA;
#pragma unroll
            for (int nt = 0; nt < 4; ++nt) {
                const int batch = nt * 16 + lr;
                const int gg = g16o ^ (batch & 7);
                float* p = (float*)(sh + (batch << 9) + (gg << 4));
#pragma unroll
                for (int r = 0; r < 4; ++r)
                    p[r] = fmaxf(acc[h][nt][r] + bvo[r], 0.0f);
            }
        }
    }
    __syncthreads();

    // ---- coalesced dump of staged 2x[64][128] fp32 ----
    {
        const int n4 = t & 31;
        const int bo = t >> 5;          // 0..15
#pragma unroll
        for (int h = 0; h < 2; ++h) {
            const char* sh = h ? (const char*)actB : (const char*)actA;
#pragma unroll
            for (int pp = 0; pp < 4; ++pp) {
                const int batch = pp * 16 + bo;
                const int gg = n4 ^ (batch & 7);
                const float4 v = *(const float4*)(sh + (batch << 9) + (gg << 4));
                ((float4*)(out + (row0 + h * 64 + batch) * 128))[n4] = v;
            }
        }
    }
}

extern "C" void kernel_launch(void* const* d_in, const int* in_sizes, int n_in,
                              void* d_out, int out_size, void* d_ws, size_t ws_size,
                              hipStream_t stream) {
    const float* x     = (const float*)d_in[0];
    const float* W_in  = (const float*)d_in[1];
    const float* b_in  = (const float*)d_in[2];
    const float* W_h   = (const float*)d_in[3];
    const float* b_h   = (const float*)d_in[4];
    const float* W_out = (const float*)d_in[5];
    const float* b_out = (const float*)d_in[6];
    float* out = (float*)d_out;

    const int B = in_sizes[0] / 512;       // 131072
    const int NP1 = B / 128;               // 1024 minmax partial blocks

    // workspace (~5.5 MB)
    __hip_bfloat16* WinT  = (__hip_bfloat16*)d_ws;           // 512*512
    __hip_bfloat16* WhT   = WinT + 512 * 512;                // 512*512
    __hip_bfloat16* WoutT = WhT + 512 * 512;                 // 128*512
    float* pmin   = (float*)(WoutT + 128 * 512);             // NP1*512
    float* pmax   = pmin + (size_t)NP1 * 512;                // NP1*512
    float* p2min  = pmax + (size_t)NP1 * 512;                // 64*512
    float* p2max  = p2min + 64 * 512;                        // 64*512
    float* cmin   = p2max + 64 * 512;                        // 512
    float* crange = cmin + 512;                              // 512
    float* sinv   = crange + 512;                            // 512

    kminmax<<<NP1, 512, 0, stream>>>(x, pmin, pmax);
    kred<<<64, 512, 0, stream>>>(pmin, pmax, p2min, p2max, NP1 / 64);
    kbounds<<<1, 512, 0, stream>>>(p2min, p2max, cmin, crange, sinv, 64,
                                   out + (size_t)B * 128);
    ktc_all<<<(2 * 512 * 512 + 128 * 512 + 255) / 256, 256, 0, stream>>>(
        W_in, W_h, W_out, WinT, WhT, WoutT);

    megamlp<<<B / 128, 512, 0, stream>>>(x, cmin, crange, sinv,
        (const u16*)WinT, (const u16*)WhT, (const u16*)WoutT,
        b_in, b_h, b_out, out);
}